// Round 5
// baseline (486.693 us; speedup 1.0000x reference)
//
#include <hip/hip_runtime.h>
#include <hip/hip_bf16.h>

#define T_DIM 512
#define S_DIM 512
#define B_DIM 8
#define E_DIM 1024
#define H_CNT 16
#define D_DIM 64
#define N_HEADS 128
#define M_ROWS 4096
#define K_DIM 1024
#define EPS_C 1e-6f

// rec_kernel LDS map (163840 B total):
#define LDS_A   0        // alpha bf16: 2 x 16 x 512 x 2 = 32768
#define LDS_P   32768    // (1-p) u16 : 2 x 16 x 512 x 2 = 32768
#define LDS_X   65536    // cpr  f32  : 2 x 16 x 512 x 4 = 65536 (swizzled chunks)
#define LDS_PCP 131072   // p*cp bf16 : 2 x 16 x 512 x 2 = 32768 (swizzled chunks)

using f32x4  = __attribute__((ext_vector_type(4))) float;
using short8 = __attribute__((ext_vector_type(8))) short;

static __device__ __forceinline__ ushort f2bf(float x){
  __hip_bfloat16 h = __float2bfloat16(x);
  return *reinterpret_cast<ushort*>(&h);
}
static __device__ __forceinline__ float rcpf(float x){
  return __builtin_amdgcn_rcpf(x);
}
static __device__ __forceinline__ uint cvt_pk_bf16(float lo, float hi){
  uint r;
  asm("v_cvt_pk_bf16_f32 %0, %1, %2" : "=v"(r) : "v"(lo), "v"(hi));
  return r;
}

template<int CTRL, int RMASK>
static __device__ __forceinline__ float dppf(float x, float oldv){
  return __int_as_float(__builtin_amdgcn_update_dpp(
      __float_as_int(oldv), __float_as_int(x), CTRL, RMASK, 0xf, false));
}
static __device__ __forceinline__ float wscan_mul(float x){
  x *= dppf<0x111,0xf>(x, 1.f);
  x *= dppf<0x112,0xf>(x, 1.f);
  x *= dppf<0x114,0xf>(x, 1.f);
  x *= dppf<0x118,0xf>(x, 1.f);
  x *= dppf<0x142,0xa>(x, 1.f);
  x *= dppf<0x143,0xc>(x, 1.f);
  return x;
}
static __device__ __forceinline__ float wscan_add(float x){
  x += dppf<0x111,0xf>(x, 0.f);
  x += dppf<0x112,0xf>(x, 0.f);
  x += dppf<0x114,0xf>(x, 0.f);
  x += dppf<0x118,0xf>(x, 0.f);
  x += dppf<0x142,0xa>(x, 0.f);
  x += dppf<0x143,0xc>(x, 0.f);
  return x;
}

// ---- batched transpose + cvt: Wt[f][e] = bf16(W[e][f]), 4 mats via z ----
__global__ __launch_bounds__(256) void wtrans4(const float* __restrict__ W0,
                                               const float* __restrict__ W1,
                                               const float* __restrict__ W2,
                                               const float* __restrict__ W3,
                                               ushort* __restrict__ T0,
                                               ushort* __restrict__ T1,
                                               ushort* __restrict__ T2,
                                               ushort* __restrict__ T3){
  const int z = blockIdx.z;
  const float* W = (z == 0) ? W0 : (z == 1) ? W1 : (z == 2) ? W2 : W3;
  ushort* Wt     = (z == 0) ? T0 : (z == 1) ? T1 : (z == 2) ? T2 : T3;
  __shared__ float tile[32][33];
  const int bx = blockIdx.x * 32, by = blockIdx.y * 32;
  const int x = threadIdx.x & 31, y = threadIdx.x >> 5;
  #pragma unroll
  for (int j = 0; j < 32; j += 8)
    tile[y + j][x] = W[(size_t)(by + y + j) * E_DIM + bx + x];
  __syncthreads();
  #pragma unroll
  for (int j = 0; j < 32; j += 8)
    Wt[(size_t)(bx + y + j) * E_DIM + by + x] = f2bf(tile[x][y + j]);
}

// ---- GEMM core: C = A x Bm(bf16 [N][K] row-major-K) ----
template<int MODE, bool ABF>
static __device__ __forceinline__ void gemm_core(const void* __restrict__ Ap,
                                                 const ushort* __restrict__ Bm,
                                                 void* __restrict__ Cout,
                                                 const float* __restrict__ bias,
                                                 int bx, int by){
  constexpr int BK = 32;
  __shared__ ushort lA[128 * BK];
  __shared__ ushort lB[128 * BK];
  const int tid = threadIdx.x;
  const int l = tid & 63, w = tid >> 6;
  const int wm = w >> 1, wn = w & 1;
  const int lq = l >> 4, lr = l & 15;
  const int m0 = by * 128, n0 = bx * 128;
  const int srow = tid >> 1, shalf = tid & 1;

  f32x4 acc[4][4];
  #pragma unroll
  for (int i = 0; i < 4; i++)
    #pragma unroll
    for (int j = 0; j < 4; j++) acc[i][j] = (f32x4){0.f, 0.f, 0.f, 0.f};

  for (int k0 = 0; k0 < K_DIM; k0 += BK){
    if constexpr (ABF){
      const ushort* ga = (const ushort*)Ap + (size_t)(m0 + srow) * K_DIM + k0 + shalf * 16;
      #pragma unroll
      for (int j = 0; j < 2; j++){
        short8 vv = *reinterpret_cast<const short8*>(ga + j * 8);
        int slot = (shalf * 2 + j) ^ (srow & 3);
        *reinterpret_cast<short8*>(reinterpret_cast<char*>(lA) + srow * 64 + slot * 16) = vv;
      }
    } else {
      const float* ga = (const float*)Ap + (size_t)(m0 + srow) * K_DIM + k0 + shalf * 16;
      ushort tmp[16];
      #pragma unroll
      for (int j = 0; j < 16; j += 4){
        float4 vv = *reinterpret_cast<const float4*>(ga + j);
        tmp[j] = f2bf(vv.x); tmp[j+1] = f2bf(vv.y); tmp[j+2] = f2bf(vv.z); tmp[j+3] = f2bf(vv.w);
      }
      #pragma unroll
      for (int j = 0; j < 2; j++){
        int slot = (shalf * 2 + j) ^ (srow & 3);
        *reinterpret_cast<short8*>(reinterpret_cast<char*>(lA) + srow * 64 + slot * 16) =
            *reinterpret_cast<short8*>(&tmp[j * 8]);
      }
    }
    {
      const ushort* gb = Bm + (size_t)(n0 + srow) * K_DIM + k0 + shalf * 16;
      #pragma unroll
      for (int j = 0; j < 2; j++){
        short8 vv = *reinterpret_cast<const short8*>(gb + j * 8);
        int slot = (shalf * 2 + j) ^ (srow & 3);
        *reinterpret_cast<short8*>(reinterpret_cast<char*>(lB) + srow * 64 + slot * 16) = vv;
      }
    }
    __syncthreads();
    short8 fa[4], fb[4];
    #pragma unroll
    for (int i = 0; i < 4; i++){
      int row = wm * 64 + i * 16 + lr;
      fa[i] = *reinterpret_cast<const short8*>(reinterpret_cast<const char*>(lA) + row * 64 + ((lq ^ (row & 3)) << 4));
      int col = wn * 64 + i * 16 + lr;
      fb[i] = *reinterpret_cast<const short8*>(reinterpret_cast<const char*>(lB) + col * 64 + ((lq ^ (col & 3)) << 4));
    }
    #pragma unroll
    for (int i = 0; i < 4; i++)
      #pragma unroll
      for (int j = 0; j < 4; j++)
        acc[i][j] = __builtin_amdgcn_mfma_f32_16x16x32_bf16(fa[i], fb[j], acc[i][j], 0, 0, 0);
    __syncthreads();
  }

  #pragma unroll
  for (int i = 0; i < 4; i++)
    #pragma unroll
    for (int j = 0; j < 4; j++)
      #pragma unroll
      for (int r = 0; r < 4; r++){
        int gm = m0 + wm * 64 + i * 16 + lq * 4 + r;
        int gn = n0 + wn * 64 + j * 16 + lr;
        float v = acc[i][j][r];
        if constexpr (MODE == 2){
          reinterpret_cast<float*>(Cout)[(size_t)gm * E_DIM + gn] = v + bias[gn];
        } else if constexpr (MODE == 3){
          int s = gm >> 3, b = gm & 7, h = gn >> 6, d = gn & 63;
          reinterpret_cast<ushort*>(Cout)[(((size_t)(b * H_CNT + h) * D_DIM + d) << 9) + s] = f2bf(v);
        } else {
          if constexpr (MODE == 1) v *= 0.125f;
          int t = gm >> 3, b = gm & 7, h = gn >> 6, d = gn & 63;
          reinterpret_cast<ushort*>(Cout)[(((size_t)(b * H_CNT + h) * T_DIM + t) << 6) + d] = f2bf(v);
        }
      }
}

__global__ __launch_bounds__(256) void gemm_qkv(const float* __restrict__ q,
                                                const float* __restrict__ k,
                                                const float* __restrict__ v,
                                                const ushort* __restrict__ wqt,
                                                const ushort* __restrict__ wkt,
                                                const ushort* __restrict__ wvt,
                                                ushort* __restrict__ qp,
                                                ushort* __restrict__ kp,
                                                ushort* __restrict__ vpT){
  if (blockIdx.z == 0)      gemm_core<1,false>(q, wqt, qp,  nullptr, blockIdx.x, blockIdx.y);
  else if (blockIdx.z == 1) gemm_core<0,false>(k, wkt, kp,  nullptr, blockIdx.x, blockIdx.y);
  else                      gemm_core<3,false>(v, wvt, vpT, nullptr, blockIdx.x, blockIdx.y);
}

__global__ __launch_bounds__(256) void gemm_out(const ushort* __restrict__ attn_bf,
                                                const ushort* __restrict__ wot,
                                                float* __restrict__ out,
                                                const float* __restrict__ bo){
  gemm_core<2,true>(attn_bf, wot, out, bo, blockIdx.x, blockIdx.y);
}

// ---- fused monotonic-attention recurrence, 4-stage pipeline ----
// Wave->SIMD is w&3, so w0 (serial R) pairs with w4 on SIMD0: w4 is kept IDLE
// to give R full issue bandwidth.  Roles: w0=R(ph-2); {w1,w2,w3,w5}=P(ph-3);
// {w6,w7}=E(ph)+X(ph-1); w4 idle. One barrier per phase.
__global__ __launch_bounds__(512) void rec_kernel(const ushort* __restrict__ qp,
                                                  const ushort* __restrict__ kp,
                                                  const ushort* __restrict__ vpT,
                                                  ushort* __restrict__ attn_bf,
                                                  const float* __restrict__ ebias_p){
  extern __shared__ char smem[];
  const int tid = threadIdx.x;
  const int l = tid & 63, w = tid >> 6;
  const int kg = l >> 4, lr = l & 15;
  const int n = blockIdx.x;
  const int bb = n >> 4, hh = n & 15;
  const float ebias = ebias_p[0];

  const ushort* qph = qp + (size_t)n * (T_DIM * D_DIM);
  const ushort* kph = kp + (size_t)n * (S_DIM * D_DIM);

  // R carry: lane l holds s = l*8 .. l*8+7
  float ap[8];
  #pragma unroll
  for (int j = 0; j < 8; j++) ap[j] = 0.f;
  if (l == 0) ap[0] = 1.f;

  // swizzled byte offsets (within a 2KB f32-row / 1KB bf16-row)
  const int xoA = (((l << 1)     ^ ((l >> 2) & 7)) << 4);  // cpr chunk0
  const int xoB = ((((l << 1)|1) ^ ((l >> 2) & 7)) << 4);  // cpr chunk1
  const int po  = ((l ^ ((l >> 3) & 7)) << 4);             // pcp 16B slot

  for (int ph = 0; ph <= 34; ++ph){
    if (w == 0){
      // ---------------- R(c): serial recurrence, slim ----------------
      const int c = ph - 2;
      if (c >= 0 && c < 32){
        const char* xb = smem + LDS_X   + ((c & 1) << 15);
        const char* cb = smem + LDS_PCP + ((c & 1) << 14);
        char*       ab = smem + LDS_A   + ((c & 1) << 14);
        f32x4 c0 = *reinterpret_cast<const f32x4*>(xb + xoA);
        f32x4 c1 = *reinterpret_cast<const f32x4*>(xb + xoB);
        uint4 pv = *reinterpret_cast<const uint4*>(cb + po);
        #pragma unroll
        for (int tt = 0; tt < 16; ++tt){
          f32x4 n0v, n1v; uint4 npv;
          if (tt < 15){
            n0v = *reinterpret_cast<const f32x4*>(xb + ((tt + 1) << 11) + xoA);
            n1v = *reinterpret_cast<const f32x4*>(xb + ((tt + 1) << 11) + xoB);
            npv = *reinterpret_cast<const uint4*>(cb + ((tt + 1) << 10) + po);
          }
          // decode pcp bf16 pairs (hi: AND, lo: SHL)
          float pc0 = __int_as_float(pv.x << 16), pc1 = __int_as_float(pv.x & 0xffff0000u);
          float pc2 = __int_as_float(pv.y << 16), pc3 = __int_as_float(pv.y & 0xffff0000u);
          float pc4 = __int_as_float(pv.z << 16), pc5 = __int_as_float(pv.z & 0xffff0000u);
          float pc6 = __int_as_float(pv.w << 16), pc7 = __int_as_float(pv.w & 0xffff0000u);
          float z0 = ap[0]*c0[0], z1 = ap[1]*c0[1], z2 = ap[2]*c0[2], z3 = ap[3]*c0[3];
          float z4 = ap[4]*c1[0], z5 = ap[5]*c1[1], z6 = ap[6]*c1[2], z7 = ap[7]*c1[3];
          // depth-3 inclusive prefix
          float a1 = z0+z1, a3 = z2+z3, a5 = z4+z5, a7 = z6+z7;
          float b3 = a1+a3, b7 = a5+a7, e6 = a5+z6;
          float d0 = z0, d1 = a1, d2 = a1+z2, d3 = b3;
          float d4 = b3+z4, d5 = b3+a5, d6 = b3+e6, d7 = b3+b7;
          float Ta = wscan_add(d7);
          float Ea = dppf<0x138,0xf>(Ta, 0.f);
          float al0 = fminf(pc0*(Ea+d0), 1.f), al1 = fminf(pc1*(Ea+d1), 1.f);
          float al2 = fminf(pc2*(Ea+d2), 1.f), al3 = fminf(pc3*(Ea+d3), 1.f);
          float al4 = fminf(pc4*(Ea+d4), 1.f), al5 = fminf(pc5*(Ea+d5), 1.f);
          float al6 = fminf(pc6*(Ea+d6), 1.f), al7 = fminf(pc7*(Ea+d7), 1.f);
          // row-sum for the mass-dump fixup (value valid at lane 63)
          float ls = ((al0+al1)+(al2+al3)) + ((al4+al5)+(al6+al7));
          float St = wscan_add(ls);
          float fx = 1.f - fminf(fmaxf(St - al7, 0.f), 1.f);
          uint4 ob;
          ob.x = cvt_pk_bf16(al0, al1);
          ob.y = cvt_pk_bf16(al2, al3);
          ob.z = cvt_pk_bf16(al4, al5);
          ob.w = cvt_pk_bf16(al6, (l == 63) ? fx : al7);
          *reinterpret_cast<uint4*>(ab + (((tt << 10) + (l << 4)) ^ ((tt & 7) << 4))) = ob;
          ap[0]=al0; ap[1]=al1; ap[2]=al2; ap[3]=al3;
          ap[4]=al4; ap[5]=al5; ap[6]=al6; ap[7]=al7;
          if (tt < 15){ c0 = n0v; c1 = n1v; pv = npv; }
        }
      }
    } else if (w >= 6){
      // ---------------- E(ce): energy -> (1-p) u16 ----------------
      const int ce = ph;
      if (ce < 32){
        const int t0 = ce << 4;
        char* pb = smem + LDS_P + ((ce & 1) << 14);
        short8 fa0 = *reinterpret_cast<const short8*>(qph + (t0 + lr) * 64 + kg * 8);
        short8 fa1 = *reinterpret_cast<const short8*>(qph + (t0 + lr) * 64 + 32 + kg * 8);
        for (int tile = w - 6; tile < 32; tile += 2){
          int s0 = tile << 4;
          short8 fb0 = *reinterpret_cast<const short8*>(kph + (s0 + lr) * 64 + kg * 8);
          short8 fb1 = *reinterpret_cast<const short8*>(kph + (s0 + lr) * 64 + 32 + kg * 8);
          f32x4 e = (f32x4){0.f, 0.f, 0.f, 0.f};
          e = __builtin_amdgcn_mfma_f32_16x16x32_bf16(fa0, fb0, e, 0, 0, 0);
          e = __builtin_amdgcn_mfma_f32_16x16x32_bf16(fa1, fb1, e, 0, 0, 0);
          #pragma unroll
          for (int r = 0; r < 4; ++r){
            float om = rcpf(1.f + __expf(e[r] + ebias));   // = 1 - sigmoid
            uint u = (uint)(om * 65535.f + 0.5f);
            *reinterpret_cast<ushort*>(pb + (((kg << 2) + r) << 10) + ((s0 + lr) << 1)) = (ushort)u;
          }
        }
      }
      // ---------------- X(cx): p -> cpr (f32, swz) + pcp (bf16, swz) ----------------
      const int cx = ph - 1;
      if (cx >= 0 && cx < 32){
        const char* pb = smem + LDS_P   + ((cx & 1) << 14);
        char*       xb = smem + LDS_X   + ((cx & 1) << 15);
        char*       cb = smem + LDS_PCP + ((cx & 1) << 14);
        for (int tt = w - 6; tt < 16; tt += 2){
          short8 uv = *reinterpret_cast<const short8*>(pb + (tt << 10) + (l << 4));
          float om[8], p[8];
          #pragma unroll
          for (int j = 0; j < 8; j++){
            om[j] = (float)(((int)uv[j]) & 0xFFFF) * (1.f / 65535.f);
            p[j] = 1.f - om[j];
          }
          float a1 = om[0]*om[1], a3 = om[2]*om[3], a5 = om[4]*om[5], a7 = om[6]*om[7];
          float b3 = a1*a3, b7 = a5*a7, e6 = a5*om[6];
          float m[8];
          m[0] = om[0]; m[1] = a1; m[2] = a1*om[2]; m[3] = b3;
          m[4] = b3*om[4]; m[5] = b3*a5; m[6] = b3*e6; m[7] = b3*b7;
          float Tm = wscan_mul(m[7]);
          float Em = dppf<0x138,0xf>(Tm, 1.f);
          float cp[8];
          cp[0] = Em;
          #pragma unroll
          for (int j = 1; j < 8; j++) cp[j] = Em * m[j-1];
          float cr[8], pc[8];
          #pragma unroll
          for (int j = 0; j < 8; j++){
            cr[j] = rcpf(fmaxf(cp[j], EPS_C));
            pc[j] = p[j] * cp[j];
          }
          *reinterpret_cast<f32x4*>(xb + (tt << 11) + xoA) = (f32x4){cr[0], cr[1], cr[2], cr[3]};
          *reinterpret_cast<f32x4*>(xb + (tt << 11) + xoB) = (f32x4){cr[4], cr[5], cr[6], cr[7]};
          uint4 pcb;
          pcb.x = cvt_pk_bf16(pc[0], pc[1]);
          pcb.y = cvt_pk_bf16(pc[2], pc[3]);
          pcb.z = cvt_pk_bf16(pc[4], pc[5]);
          pcb.w = cvt_pk_bf16(pc[6], pc[7]);
          *reinterpret_cast<uint4*>(cb + (tt << 10) + po) = pcb;
        }
      }
    } else if (w != 4){
      // ---------------- P(c): alpha x V -> attn (bf16) ----------------
      const int c = ph - 3;
      if (c >= 0){
        const int widx = (w == 5) ? 3 : (w - 1);
        const int dcol = (widx << 4) + lr;
        const ushort* vb = vpT + ((size_t)n * 64 + dcol) * 512;
        const char* ab = smem + LDS_A + ((c & 1) << 14);
        f32x4 ac0 = (f32x4){0.f, 0.f, 0.f, 0.f};
        f32x4 ac1 = (f32x4){0.f, 0.f, 0.f, 0.f};
        #pragma unroll
        for (int kk = 0; kk < 8; ++kk){
          int sbA = (2*kk)   * 32 + kg * 8;
          int sbB = (2*kk+1) * 32 + kg * 8;
          short8 faA = *reinterpret_cast<const short8*>(ab + (((lr << 10) + (sbA << 1)) ^ ((lr & 7) << 4)));
          short8 fbA = *reinterpret_cast<const short8*>(vb + sbA);
          ac0 = __builtin_amdgcn_mfma_f32_16x16x32_bf16(faA, fbA, ac0, 0, 0, 0);
          short8 faB = *reinterpret_cast<const short8*>(ab + (((lr << 10) + (sbB << 1)) ^ ((lr & 7) << 4)));
          short8 fbB = *reinterpret_cast<const short8*>(vb + sbB);
          ac1 = __builtin_amdgcn_mfma_f32_16x16x32_bf16(faB, fbB, ac1, 0, 0, 0);
        }
        const int t0 = c << 4;
        #pragma unroll
        for (int r = 0; r < 4; ++r){
          int tg = t0 + (kg << 2) + r;
          attn_bf[((size_t)tg * B_DIM + bb) * E_DIM + hh * 64 + dcol] = f2bf(ac0[r] + ac1[r]);
        }
      }
    }
    __syncthreads();
  }
}

extern "C" void kernel_launch(void* const* d_in, const int* in_sizes, int n_in,
                              void* d_out, int out_size, void* d_ws, size_t ws_size,
                              hipStream_t stream){
  (void)in_sizes; (void)n_in; (void)out_size; (void)ws_size;
  const float* q  = (const float*)d_in[0];
  const float* k  = (const float*)d_in[1];
  const float* v  = (const float*)d_in[2];
  const float* Wq = (const float*)d_in[3];
  const float* Wk = (const float*)d_in[4];
  const float* Wv = (const float*)d_in[5];
  const float* Wo = (const float*)d_in[6];
  const float* bo = (const float*)d_in[7];
  const float* eb = (const float*)d_in[8];

  char* ws = (char*)d_ws;
  ushort* wqt  = (ushort*)(ws);
  ushort* wkt  = (ushort*)(ws + (1u << 21));
  ushort* wvt  = (ushort*)(ws + 2u * (1u << 21));
  ushort* wot  = (ushort*)(ws + 3u * (1u << 21));
  ushort* qp   = (ushort*)(ws + 4u * (1u << 21));
  ushort* kp   = (ushort*)(ws + 4u * (1u << 21) + (1u << 23));
  ushort* vpT  = (ushort*)(ws + 4u * (1u << 21) + 2u * (1u << 23));
  ushort* attn = (ushort*)(ws + 4u * (1u << 21) + 3u * (1u << 23));

  wtrans4<<<dim3(32, 32, 4), dim3(256), 0, stream>>>(Wq, Wk, Wv, Wo, wqt, wkt, wvt, wot);

  gemm_qkv<<<dim3(E_DIM / 128, M_ROWS / 128, 3), dim3(256), 0, stream>>>(
      q, k, v, wqt, wkt, wvt, qp, kp, vpT);

  hipFuncSetAttribute((const void*)rec_kernel,
                      hipFuncAttributeMaxDynamicSharedMemorySize, 163840);
  rec_kernel<<<dim3(N_HEADS), dim3(512), 163840, stream>>>(qp, kp, vpT, attn, eb);

  gemm_out<<<dim3(E_DIM / 128, M_ROWS / 128), dim3(256), 0, stream>>>(attn, wot, (float*)d_out, bo);
}

// Round 7
// 369.124 us; speedup vs baseline: 1.3185x; 1.3185x over previous
//
#include <hip/hip_runtime.h>
#include <hip/hip_bf16.h>

#define T_DIM 512
#define S_DIM 512
#define B_DIM 8
#define E_DIM 1024
#define H_CNT 16
#define D_DIM 64
#define N_HEADS 128
#define M_ROWS 4096
#define K_DIM 1024
#define EPS_C 1e-6f

// rec_kernel LDS map (163840 B total):
#define LDS_A   0        // alpha bf16: 2 x 16 x 512 x 2 = 32768
#define LDS_P   32768    // (1-p) u16 : 2 x 16 x 512 x 2 = 32768
#define LDS_X   65536    // cpr  f32  : 2 x 16 x 512 x 4 = 65536 (swizzled chunks)
#define LDS_PCP 131072   // p*cp bf16 : 2 x 16 x 512 x 2 = 32768 (swizzled chunks)

using f32x4  = __attribute__((ext_vector_type(4))) float;
using short8 = __attribute__((ext_vector_type(8))) short;

static __device__ __forceinline__ ushort f2bf(float x){
  __hip_bfloat16 h = __float2bfloat16(x);
  return *reinterpret_cast<ushort*>(&h);
}
static __device__ __forceinline__ float rcpf(float x){
  return __builtin_amdgcn_rcpf(x);
}
static __device__ __forceinline__ uint cvt_pk_bf16(float lo, float hi){
  uint r;
  asm("v_cvt_pk_bf16_f32 %0, %1, %2" : "=v"(r) : "v"(lo), "v"(hi));
  return r;
}

template<int CTRL, int RMASK>
static __device__ __forceinline__ float dppf(float x, float oldv){
  return __int_as_float(__builtin_amdgcn_update_dpp(
      __float_as_int(oldv), __float_as_int(x), CTRL, RMASK, 0xf, false));
}
static __device__ __forceinline__ float wscan_mul(float x){
  x *= dppf<0x111,0xf>(x, 1.f);
  x *= dppf<0x112,0xf>(x, 1.f);
  x *= dppf<0x114,0xf>(x, 1.f);
  x *= dppf<0x118,0xf>(x, 1.f);
  x *= dppf<0x142,0xa>(x, 1.f);
  x *= dppf<0x143,0xc>(x, 1.f);
  return x;
}
static __device__ __forceinline__ float wscan_add(float x){
  x += dppf<0x111,0xf>(x, 0.f);
  x += dppf<0x112,0xf>(x, 0.f);
  x += dppf<0x114,0xf>(x, 0.f);
  x += dppf<0x118,0xf>(x, 0.f);
  x += dppf<0x142,0xa>(x, 0.f);
  x += dppf<0x143,0xc>(x, 0.f);
  return x;
}

// ---- batched transpose + cvt: Wt[f][e] = bf16(W[e][f]), 4 mats via z ----
__global__ __launch_bounds__(256) void wtrans4(const float* __restrict__ W0,
                                               const float* __restrict__ W1,
                                               const float* __restrict__ W2,
                                               const float* __restrict__ W3,
                                               ushort* __restrict__ T0,
                                               ushort* __restrict__ T1,
                                               ushort* __restrict__ T2,
                                               ushort* __restrict__ T3){
  const int z = blockIdx.z;
  const float* W = (z == 0) ? W0 : (z == 1) ? W1 : (z == 2) ? W2 : W3;
  ushort* Wt     = (z == 0) ? T0 : (z == 1) ? T1 : (z == 2) ? T2 : T3;
  __shared__ float tile[32][33];
  const int bx = blockIdx.x * 32, by = blockIdx.y * 32;
  const int x = threadIdx.x & 31, y = threadIdx.x >> 5;
  #pragma unroll
  for (int j = 0; j < 32; j += 8)
    tile[y + j][x] = W[(size_t)(by + y + j) * E_DIM + bx + x];
  __syncthreads();
  #pragma unroll
  for (int j = 0; j < 32; j += 8)
    Wt[(size_t)(bx + y + j) * E_DIM + by + x] = f2bf(tile[x][y + j]);
}

// ---- GEMM core: C = A x Bm(bf16 [N][K] row-major-K) ----
template<int MODE, bool ABF>
static __device__ __forceinline__ void gemm_core(const void* __restrict__ Ap,
                                                 const ushort* __restrict__ Bm,
                                                 void* __restrict__ Cout,
                                                 const float* __restrict__ bias,
                                                 int bx, int by){
  constexpr int BK = 32;
  __shared__ ushort lA[128 * BK];
  __shared__ ushort lB[128 * BK];
  const int tid = threadIdx.x;
  const int l = tid & 63, w = tid >> 6;
  const int wm = w >> 1, wn = w & 1;
  const int lq = l >> 4, lr = l & 15;
  const int m0 = by * 128, n0 = bx * 128;
  const int srow = tid >> 1, shalf = tid & 1;

  f32x4 acc[4][4];
  #pragma unroll
  for (int i = 0; i < 4; i++)
    #pragma unroll
    for (int j = 0; j < 4; j++) acc[i][j] = (f32x4){0.f, 0.f, 0.f, 0.f};

  for (int k0 = 0; k0 < K_DIM; k0 += BK){
    if constexpr (ABF){
      const ushort* ga = (const ushort*)Ap + (size_t)(m0 + srow) * K_DIM + k0 + shalf * 16;
      #pragma unroll
      for (int j = 0; j < 2; j++){
        short8 vv = *reinterpret_cast<const short8*>(ga + j * 8);
        int slot = (shalf * 2 + j) ^ (srow & 3);
        *reinterpret_cast<short8*>(reinterpret_cast<char*>(lA) + srow * 64 + slot * 16) = vv;
      }
    } else {
      const float* ga = (const float*)Ap + (size_t)(m0 + srow) * K_DIM + k0 + shalf * 16;
      ushort tmp[16];
      #pragma unroll
      for (int j = 0; j < 16; j += 4){
        float4 vv = *reinterpret_cast<const float4*>(ga + j);
        tmp[j] = f2bf(vv.x); tmp[j+1] = f2bf(vv.y); tmp[j+2] = f2bf(vv.z); tmp[j+3] = f2bf(vv.w);
      }
      #pragma unroll
      for (int j = 0; j < 2; j++){
        int slot = (shalf * 2 + j) ^ (srow & 3);
        *reinterpret_cast<short8*>(reinterpret_cast<char*>(lA) + srow * 64 + slot * 16) =
            *reinterpret_cast<short8*>(&tmp[j * 8]);
      }
    }
    {
      const ushort* gb = Bm + (size_t)(n0 + srow) * K_DIM + k0 + shalf * 16;
      #pragma unroll
      for (int j = 0; j < 2; j++){
        short8 vv = *reinterpret_cast<const short8*>(gb + j * 8);
        int slot = (shalf * 2 + j) ^ (srow & 3);
        *reinterpret_cast<short8*>(reinterpret_cast<char*>(lB) + srow * 64 + slot * 16) = vv;
      }
    }
    __syncthreads();
    short8 fa[4], fb[4];
    #pragma unroll
    for (int i = 0; i < 4; i++){
      int row = wm * 64 + i * 16 + lr;
      fa[i] = *reinterpret_cast<const short8*>(reinterpret_cast<const char*>(lA) + row * 64 + ((lq ^ (row & 3)) << 4));
      int col = wn * 64 + i * 16 + lr;
      fb[i] = *reinterpret_cast<const short8*>(reinterpret_cast<const char*>(lB) + col * 64 + ((lq ^ (col & 3)) << 4));
    }
    #pragma unroll
    for (int i = 0; i < 4; i++)
      #pragma unroll
      for (int j = 0; j < 4; j++)
        acc[i][j] = __builtin_amdgcn_mfma_f32_16x16x32_bf16(fa[i], fb[j], acc[i][j], 0, 0, 0);
    __syncthreads();
  }

  #pragma unroll
  for (int i = 0; i < 4; i++)
    #pragma unroll
    for (int j = 0; j < 4; j++)
      #pragma unroll
      for (int r = 0; r < 4; r++){
        int gm = m0 + wm * 64 + i * 16 + lq * 4 + r;
        int gn = n0 + wn * 64 + j * 16 + lr;
        float v = acc[i][j][r];
        if constexpr (MODE == 2){
          reinterpret_cast<float*>(Cout)[(size_t)gm * E_DIM + gn] = v + bias[gn];
        } else if constexpr (MODE == 3){
          int s = gm >> 3, b = gm & 7, h = gn >> 6, d = gn & 63;
          reinterpret_cast<ushort*>(Cout)[(((size_t)(b * H_CNT + h) * D_DIM + d) << 9) + s] = f2bf(v);
        } else {
          if constexpr (MODE == 1) v *= 0.125f;
          int t = gm >> 3, b = gm & 7, h = gn >> 6, d = gn & 63;
          reinterpret_cast<ushort*>(Cout)[(((size_t)(b * H_CNT + h) * T_DIM + t) << 6) + d] = f2bf(v);
        }
      }
}

__global__ __launch_bounds__(256) void gemm_qkv(const float* __restrict__ q,
                                                const float* __restrict__ k,
                                                const float* __restrict__ v,
                                                const ushort* __restrict__ wqt,
                                                const ushort* __restrict__ wkt,
                                                const ushort* __restrict__ wvt,
                                                ushort* __restrict__ qp,
                                                ushort* __restrict__ kp,
                                                ushort* __restrict__ vpT){
  if (blockIdx.z == 0)      gemm_core<1,false>(q, wqt, qp,  nullptr, blockIdx.x, blockIdx.y);
  else if (blockIdx.z == 1) gemm_core<0,false>(k, wkt, kp,  nullptr, blockIdx.x, blockIdx.y);
  else                      gemm_core<3,false>(v, wvt, vpT, nullptr, blockIdx.x, blockIdx.y);
}

__global__ __launch_bounds__(256) void gemm_out(const ushort* __restrict__ attn_bf,
                                                const ushort* __restrict__ wot,
                                                float* __restrict__ out,
                                                const float* __restrict__ bo){
  gemm_core<2,true>(attn_bf, wot, out, bo, blockIdx.x, blockIdx.y);
}

// ---- fused monotonic-attention recurrence, 4-stage pipeline ----
// Roles: w0=R(ph-2); {w1,w2,w3,w5}=P(ph-3); {w6,w7}=E(ph)+X(ph-1); w4 idle
// (SIMD0 partner of w0). E waves hold the K head (16 tiles x 32B/lane = 128
// VGPR) and P waves hold their V columns (64 VGPR) in persistent registers
// loaded once in the prologue — per-phase E/P do ZERO global loads, removing
// the ~200cyc/tile L2-latency serial chain that r5's post-mortem identified
// as the phase critical path (phase time scaled 1.48x with per-E-wave tiles).
__global__ __launch_bounds__(512) void rec_kernel(const ushort* __restrict__ qp,
                                                  const ushort* __restrict__ kp,
                                                  const ushort* __restrict__ vpT,
                                                  ushort* __restrict__ attn_bf,
                                                  const float* __restrict__ ebias_p){
  extern __shared__ char smem[];
  const int tid = threadIdx.x;
  const int l = tid & 63, w = tid >> 6;
  const int kg = l >> 4, lr = l & 15;
  const int n = blockIdx.x;
  const int bb = n >> 4, hh = n & 15;
  const float ebias = ebias_p[0];

  const ushort* qph = qp + (size_t)n * (T_DIM * D_DIM);
  const ushort* kph = kp + (size_t)n * (S_DIM * D_DIM);

  // R carry: lane l holds s = l*8 .. l*8+7
  float ap[8];
  #pragma unroll
  for (int j = 0; j < 8; j++) ap[j] = 0.f;
  if (l == 0) ap[0] = 1.f;

  // swizzled byte offsets (within a 2KB f32-row / 1KB bf16-row)
  const int xoA = (((l << 1)     ^ ((l >> 2) & 7)) << 4);  // cpr chunk0
  const int xoB = ((((l << 1)|1) ^ ((l >> 2) & 7)) << 4);  // cpr chunk1
  const int po  = ((l ^ ((l >> 3) & 7)) << 4);             // pcp 16B slot

  // P-wave geometry (valid when w in {1,2,3,5})
  const int widx = (w == 5) ? 3 : (w - 1);
  const int dcol = (widx << 4) + lr;
  const ushort* vb = vpT + ((size_t)n * 64 + dcol) * 512;

  // ---- persistent register fragments (prologue, loaded once) ----
  short8 kf0[16], kf1[16];   // E waves: K tiles (w-6 + 2u)
  short8 vf0[8],  vf1[8];    // P waves: V column-slices
  if (w >= 6){
    #pragma unroll
    for (int u = 0; u < 16; u++){
      const ushort* kr = kph + ((((w - 6) + 2 * u) << 4) + lr) * 64 + kg * 8;
      kf0[u] = *reinterpret_cast<const short8*>(kr);
      kf1[u] = *reinterpret_cast<const short8*>(kr + 32);
    }
  } else if (w != 0 && w != 4){
    #pragma unroll
    for (int kk = 0; kk < 8; kk++){
      vf0[kk] = *reinterpret_cast<const short8*>(vb + (2 * kk)     * 32 + kg * 8);
      vf1[kk] = *reinterpret_cast<const short8*>(vb + (2 * kk + 1) * 32 + kg * 8);
    }
  }

  for (int ph = 0; ph <= 34; ++ph){
    if (w == 0){
      // ---------------- R(c): serial recurrence, slim ----------------
      const int c = ph - 2;
      if (c >= 0 && c < 32){
        const char* xb = smem + LDS_X   + ((c & 1) << 15);
        const char* cb = smem + LDS_PCP + ((c & 1) << 14);
        char*       ab = smem + LDS_A   + ((c & 1) << 14);
        f32x4 c0 = *reinterpret_cast<const f32x4*>(xb + xoA);
        f32x4 c1 = *reinterpret_cast<const f32x4*>(xb + xoB);
        uint4 pv = *reinterpret_cast<const uint4*>(cb + po);
        #pragma unroll
        for (int tt = 0; tt < 16; ++tt){
          f32x4 n0v, n1v; uint4 npv;
          if (tt < 15){
            n0v = *reinterpret_cast<const f32x4*>(xb + ((tt + 1) << 11) + xoA);
            n1v = *reinterpret_cast<const f32x4*>(xb + ((tt + 1) << 11) + xoB);
            npv = *reinterpret_cast<const uint4*>(cb + ((tt + 1) << 10) + po);
          }
          // decode pcp bf16 pairs (hi: AND, lo: SHL)
          float pc0 = __int_as_float(pv.x << 16), pc1 = __int_as_float(pv.x & 0xffff0000u);
          float pc2 = __int_as_float(pv.y << 16), pc3 = __int_as_float(pv.y & 0xffff0000u);
          float pc4 = __int_as_float(pv.z << 16), pc5 = __int_as_float(pv.z & 0xffff0000u);
          float pc6 = __int_as_float(pv.w << 16), pc7 = __int_as_float(pv.w & 0xffff0000u);
          float z0 = ap[0]*c0[0], z1 = ap[1]*c0[1], z2 = ap[2]*c0[2], z3 = ap[3]*c0[3];
          float z4 = ap[4]*c1[0], z5 = ap[5]*c1[1], z6 = ap[6]*c1[2], z7 = ap[7]*c1[3];
          // depth-3 inclusive prefix
          float a1 = z0+z1, a3 = z2+z3, a5 = z4+z5, a7 = z6+z7;
          float b3 = a1+a3, b7 = a5+a7, e6 = a5+z6;
          float d0 = z0, d1 = a1, d2 = a1+z2, d3 = b3;
          float d4 = b3+z4, d5 = b3+a5, d6 = b3+e6, d7 = b3+b7;
          float Ta = wscan_add(d7);
          float Ea = dppf<0x138,0xf>(Ta, 0.f);
          float al0 = fminf(pc0*(Ea+d0), 1.f), al1 = fminf(pc1*(Ea+d1), 1.f);
          float al2 = fminf(pc2*(Ea+d2), 1.f), al3 = fminf(pc3*(Ea+d3), 1.f);
          float al4 = fminf(pc4*(Ea+d4), 1.f), al5 = fminf(pc5*(Ea+d5), 1.f);
          float al6 = fminf(pc6*(Ea+d6), 1.f), al7 = fminf(pc7*(Ea+d7), 1.f);
          // row-sum for the mass-dump fixup (value valid at lane 63)
          float ls = ((al0+al1)+(al2+al3)) + ((al4+al5)+(al6+al7));
          float St = wscan_add(ls);
          float fx = 1.f - fminf(fmaxf(St - al7, 0.f), 1.f);
          uint4 ob;
          ob.x = cvt_pk_bf16(al0, al1);
          ob.y = cvt_pk_bf16(al2, al3);
          ob.z = cvt_pk_bf16(al4, al5);
          ob.w = cvt_pk_bf16(al6, (l == 63) ? fx : al7);
          *reinterpret_cast<uint4*>(ab + (((tt << 10) + (l << 4)) ^ ((tt & 7) << 4))) = ob;
          ap[0]=al0; ap[1]=al1; ap[2]=al2; ap[3]=al3;
          ap[4]=al4; ap[5]=al5; ap[6]=al6; ap[7]=al7;
          if (tt < 15){ c0 = n0v; c1 = n1v; pv = npv; }
        }
      }
    } else if (w >= 6){
      // ---------------- E(ce): energy -> (1-p) u16 (K from registers) ----------------
      const int ce = ph;
      if (ce < 32){
        const int t0 = ce << 4;
        char* pb = smem + LDS_P + ((ce & 1) << 14);
        short8 fa0 = *reinterpret_cast<const short8*>(qph + (t0 + lr) * 64 + kg * 8);
        short8 fa1 = *reinterpret_cast<const short8*>(qph + (t0 + lr) * 64 + 32 + kg * 8);
        #pragma unroll
        for (int u = 0; u < 16; u++){
          int s0 = ((w - 6) + 2 * u) << 4;
          f32x4 e = (f32x4){0.f, 0.f, 0.f, 0.f};
          e = __builtin_amdgcn_mfma_f32_16x16x32_bf16(fa0, kf0[u], e, 0, 0, 0);
          e = __builtin_amdgcn_mfma_f32_16x16x32_bf16(fa1, kf1[u], e, 0, 0, 0);
          #pragma unroll
          for (int r = 0; r < 4; ++r){
            float om = rcpf(1.f + __expf(e[r] + ebias));   // = 1 - sigmoid
            uint uu = (uint)(om * 65535.f + 0.5f);
            *reinterpret_cast<ushort*>(pb + (((kg << 2) + r) << 10) + ((s0 + lr) << 1)) = (ushort)uu;
          }
        }
      }
      // ---------------- X(cx): p -> cpr (f32, swz) + pcp (bf16, swz) ----------------
      const int cx = ph - 1;
      if (cx >= 0 && cx < 32){
        const char* pb = smem + LDS_P   + ((cx & 1) << 14);
        char*       xb = smem + LDS_X   + ((cx & 1) << 15);
        char*       cb = smem + LDS_PCP + ((cx & 1) << 14);
        for (int tt = w - 6; tt < 16; tt += 2){
          short8 uv = *reinterpret_cast<const short8*>(pb + (tt << 10) + (l << 4));
          float om[8], p[8];
          #pragma unroll
          for (int j = 0; j < 8; j++){
            om[j] = (float)(((int)uv[j]) & 0xFFFF) * (1.f / 65535.f);
            p[j] = 1.f - om[j];
          }
          float a1 = om[0]*om[1], a3 = om[2]*om[3], a5 = om[4]*om[5], a7 = om[6]*om[7];
          float b3 = a1*a3, b7 = a5*a7, e6 = a5*om[6];
          float m[8];
          m[0] = om[0]; m[1] = a1; m[2] = a1*om[2]; m[3] = b3;
          m[4] = b3*om[4]; m[5] = b3*a5; m[6] = b3*e6; m[7] = b3*b7;
          float Tm = wscan_mul(m[7]);
          float Em = dppf<0x138,0xf>(Tm, 1.f);
          float cp[8];
          cp[0] = Em;
          #pragma unroll
          for (int j = 1; j < 8; j++) cp[j] = Em * m[j-1];
          float cr[8], pc[8];
          #pragma unroll
          for (int j = 0; j < 8; j++){
            cr[j] = rcpf(fmaxf(cp[j], EPS_C));
            pc[j] = p[j] * cp[j];
          }
          *reinterpret_cast<f32x4*>(xb + (tt << 11) + xoA) = (f32x4){cr[0], cr[1], cr[2], cr[3]};
          *reinterpret_cast<f32x4*>(xb + (tt << 11) + xoB) = (f32x4){cr[4], cr[5], cr[6], cr[7]};
          uint4 pcb;
          pcb.x = cvt_pk_bf16(pc[0], pc[1]);
          pcb.y = cvt_pk_bf16(pc[2], pc[3]);
          pcb.z = cvt_pk_bf16(pc[4], pc[5]);
          pcb.w = cvt_pk_bf16(pc[6], pc[7]);
          *reinterpret_cast<uint4*>(cb + (tt << 10) + po) = pcb;
        }
      }
    } else if (w != 4){
      // ---------------- P(c): alpha x V -> attn (bf16, V from registers) ----------------
      const int c = ph - 3;
      if (c >= 0){
        const char* ab = smem + LDS_A + ((c & 1) << 14);
        f32x4 ac0 = (f32x4){0.f, 0.f, 0.f, 0.f};
        f32x4 ac1 = (f32x4){0.f, 0.f, 0.f, 0.f};
        #pragma unroll
        for (int kk = 0; kk < 8; ++kk){
          int sbA = (2*kk)   * 32 + kg * 8;
          int sbB = (2*kk+1) * 32 + kg * 8;
          short8 faA = *reinterpret_cast<const short8*>(ab + (((lr << 10) + (sbA << 1)) ^ ((lr & 7) << 4)));
          ac0 = __builtin_amdgcn_mfma_f32_16x16x32_bf16(faA, vf0[kk], ac0, 0, 0, 0);
          short8 faB = *reinterpret_cast<const short8*>(ab + (((lr << 10) + (sbB << 1)) ^ ((lr & 7) << 4)));
          ac1 = __builtin_amdgcn_mfma_f32_16x16x32_bf16(faB, vf1[kk], ac1, 0, 0, 0);
        }
        const int t0 = c << 4;
        #pragma unroll
        for (int r = 0; r < 4; ++r){
          int tg = t0 + (kg << 2) + r;
          attn_bf[((size_t)tg * B_DIM + bb) * E_DIM + hh * 64 + dcol] = f2bf(ac0[r] + ac1[r]);
        }
      }
    }
    __syncthreads();
  }
}

extern "C" void kernel_launch(void* const* d_in, const int* in_sizes, int n_in,
                              void* d_out, int out_size, void* d_ws, size_t ws_size,
                              hipStream_t stream){
  (void)in_sizes; (void)n_in; (void)out_size; (void)ws_size;
  const float* q  = (const float*)d_in[0];
  const float* k  = (const float*)d_in[1];
  const float* v  = (const float*)d_in[2];
  const float* Wq = (const float*)d_in[3];
  const float* Wk = (const float*)d_in[4];
  const float* Wv = (const float*)d_in[5];
  const float* Wo = (const float*)d_in[6];
  const float* bo = (const float*)d_in[7];
  const float* eb = (const float*)d_in[8];

  char* ws = (char*)d_ws;
  ushort* wqt  = (ushort*)(ws);
  ushort* wkt  = (ushort*)(ws + (1u << 21));
  ushort* wvt  = (ushort*)(ws + 2u * (1u << 21));
  ushort* wot  = (ushort*)(ws + 3u * (1u << 21));
  ushort* qp   = (ushort*)(ws + 4u * (1u << 21));
  ushort* kp   = (ushort*)(ws + 4u * (1u << 21) + (1u << 23));
  ushort* vpT  = (ushort*)(ws + 4u * (1u << 21) + 2u * (1u << 23));
  ushort* attn = (ushort*)(ws + 4u * (1u << 21) + 3u * (1u << 23));

  wtrans4<<<dim3(32, 32, 4), dim3(256), 0, stream>>>(Wq, Wk, Wv, Wo, wqt, wkt, wvt, wot);

  gemm_qkv<<<dim3(E_DIM / 128, M_ROWS / 128, 3), dim3(256), 0, stream>>>(
      q, k, v, wqt, wkt, wvt, qp, kp, vpT);

  hipFuncSetAttribute((const void*)rec_kernel,
                      hipFuncAttributeMaxDynamicSharedMemorySize, 163840);
  rec_kernel<<<dim3(N_HEADS), dim3(512), 163840, stream>>>(qp, kp, vpT, attn, eb);

  gemm_out<<<dim3(E_DIM / 128, M_ROWS / 128), dim3(256), 0, stream>>>(attn, wot, (float*)d_out, bo);
}